// Round 3
// baseline (157.892 us; speedup 1.0000x reference)
//
#include <hip/hip_runtime.h>
#include <cmath>

#define S_SEQ 4096
#define HD 1024
#define NG 3072           // 3*H
#define CHR 32            // rows per scan chunk
#define NCH 128           // chunks (CHR*NCH = 4096)
#define K1 2048           // GEMM1 K
#define NT1 (K1 / 64)     // 32 K-tiles of 64

typedef _Float16 half8_t __attribute__((ext_vector_type(8)));
typedef _Float16 half4_t __attribute__((ext_vector_type(4)));
typedef float f32x4_t __attribute__((ext_vector_type(4)));

__device__ __forceinline__ void gload_lds16(const void* g, void* l) {
  __builtin_amdgcn_global_load_lds(
      (const __attribute__((address_space(1))) void*)g,
      (__attribute__((address_space(3))) void*)l, 16, 0, 0);
}

__device__ __forceinline__ float sigmoidf_(float x) {
  return 1.f / (1.f + __expf(-x));
}
__device__ __forceinline__ float tanhf_(float x) {
  return 1.f - 2.f / (__expf(2.f * x) + 1.f);
}

// ---------------- flat f32 -> fp16 conversion ----------------
__global__ void conv_f32_f16(const float* __restrict__ src,
                             _Float16* __restrict__ dst, int n4) {
  int i = blockIdx.x * 256 + threadIdx.x;
  if (i >= n4) return;
  float4 v = *(const float4*)(src + (size_t)i * 4);
  half4_t h;
  h[0] = (_Float16)v.x; h[1] = (_Float16)v.y;
  h[2] = (_Float16)v.z; h[3] = (_Float16)v.w;
  *(half4_t*)(dst + (size_t)i * 4) = h;
}

// ---------------- scan_x: A=[x | s_local] fp16, xsum=chunk sums fp16 -------
__global__ void scan_x(const float* __restrict__ x, _Float16* __restrict__ A,
                       _Float16* __restrict__ xsum) {
  int j = blockIdx.x * 256 + threadIdx.x;   // column 0..1023
  int c = blockIdx.y;                        // chunk 0..127
  int t0 = c * CHR;
  float run = 0.f;
  for (int t = t0; t < t0 + CHR; ++t) {
    float v = x[(size_t)t * HD + j];
    A[(size_t)t * 2048 + j]        = (_Float16)v;
    A[(size_t)t * 2048 + 1024 + j] = (_Float16)run;
    run += v;
  }
  xsum[(size_t)c * HD + j] = (_Float16)run;
}

// ---------------- exclusive scan over chunk partials + b1 fold -------------
__global__ void scan_part(const float* __restrict__ praw,
                          const float* __restrict__ b1,
                          float* __restrict__ pout) {
  int j = blockIdx.x * 256 + threadIdx.x;   // 0..3071
  float run = b1[j];
  for (int c = 0; c < NCH; ++c) {
    float v = praw[(size_t)c * NG + j];
    pout[(size_t)c * NG + j] = run;
    run += v;
  }
}

// ---------------- small 2-phase GEMM (partGEMM + GEMM2) --------------------
// MODE 0: C[row*N+col] = acc
// MODE 1: out[idx] = (acc + bias[col]) * (float)mulh[idx]
template <int MODE>
__global__ __launch_bounds__(256, 2)
void gemm_bt(const _Float16* __restrict__ A, const _Float16* __restrict__ B,
             int M, int N, int K, int ldb,
             float* __restrict__ C,
             const float* __restrict__ bias, const _Float16* __restrict__ mulh,
             float* __restrict__ out) {
  __shared__ _Float16 As[128 * 32];
  __shared__ _Float16 Bs[128 * 32];

  const int tid = threadIdx.x;
  const int lane = tid & 63;
  const int wid = tid >> 6;
  const int wr = wid >> 1;
  const int wc = wid & 1;

  const int m0 = blockIdx.y * 128;
  const int n0 = blockIdx.x * 128;

  const int srow = lane >> 2;
  const int scol = (lane & 3) << 3;

  const _Float16* gA = A + (size_t)(m0 + wid * 32 + srow) * K + scol;
  const _Float16* gB = B + (size_t)(n0 + wid * 32 + srow) * ldb + scol;
  _Float16* lA = As + (wid * 32) * 32;
  _Float16* lB = Bs + (wid * 32) * 32;

  f32x4_t acc[4][4] = {};

  const int fr = lane & 15;
  const int fk = (lane >> 4) << 3;

  for (int kk = 0; kk < K; kk += 32) {
    gload_lds16(gA + kk,                  lA);
    gload_lds16(gA + kk + (size_t)16*K,   lA + 16 * 32);
    gload_lds16(gB + kk,                  lB);
    gload_lds16(gB + kk + (size_t)16*ldb, lB + 16 * 32);
    __syncthreads();

    half8_t af[4], bf[4];
#pragma unroll
    for (int m = 0; m < 4; ++m)
      af[m] = *(const half8_t*)&As[(wr * 64 + m * 16 + fr) * 32 + fk];
#pragma unroll
    for (int n = 0; n < 4; ++n)
      bf[n] = *(const half8_t*)&Bs[(wc * 64 + n * 16 + fr) * 32 + fk];
#pragma unroll
    for (int m = 0; m < 4; ++m)
#pragma unroll
      for (int n = 0; n < 4; ++n)
        acc[m][n] = __builtin_amdgcn_mfma_f32_16x16x32_f16(af[m], bf[n],
                                                           acc[m][n], 0, 0, 0);
    __syncthreads();
  }

  const int crow = m0 + wr * 64 + ((lane >> 4) << 2);
  const int ccol = n0 + wc * 64 + (lane & 15);
#pragma unroll
  for (int m = 0; m < 4; ++m)
#pragma unroll
    for (int n = 0; n < 4; ++n) {
      const int col = ccol + n * 16;
#pragma unroll
      for (int r = 0; r < 4; ++r) {
        const int row = crow + m * 16 + r;
        const float v = acc[m][n][r];
        if (MODE == 0) {
          C[(size_t)row * N + col] = v;
        } else {
          size_t idx = (size_t)row * N + col;
          out[idx] = (v + bias[col]) * (float)mulh[idx];
        }
      }
    }
}

// ---------------- GEMM1: 256x256 tile, 8-phase, counted vmcnt --------------
// gates[4096,3072] = Ah[4096,2048] @ w1h[3072,2048]^T + part[(row>>5)][col]
// epilogue: region 0 -> sigmoid -> igb fp16 ; 1 -> sigmoid -> out0 f32 ;
//           2 -> tanh -> th fp16
#define BARX __builtin_amdgcn_s_barrier()
#define PR1 __builtin_amdgcn_s_setprio(1)
#define PR0 __builtin_amdgcn_s_setprio(0)
#define VM8 asm volatile("s_waitcnt vmcnt(8)" ::: "memory")

__global__ __launch_bounds__(512, 2)
void gemm1_8ph(const _Float16* __restrict__ A, const _Float16* __restrict__ B,
               const float* __restrict__ part, _Float16* __restrict__ igb,
               float* __restrict__ out0, _Float16* __restrict__ th) {
  __shared__ __align__(16) _Float16 sA[2][256 * 64];
  __shared__ __align__(16) _Float16 sB[2][256 * 64];

  const int tid = threadIdx.x;
  const int l = tid & 63;
  const int w = tid >> 6;          // 0..7
  const int wr = w >> 2;           // 0..1  (M half)
  const int wc = w & 3;            // 0..3  (N quarter)

  // bijective XCD swizzle: 192 blocks, 192 % 8 == 0
  const int id = blockIdx.x;
  const int swz = (id & 7) * 24 + (id >> 3);
  const int bx = swz % 12;         // N tile
  const int by = swz / 12;         // M tile
  const int m0 = by * 256;
  const int n0 = bx * 256;

  // staging: per wave rows [w*32, w*32+32); per gload 8 rows x 128B
  const int lr = l >> 3;                       // 0..7 row in octet
  const int lcs = ((l & 7) ^ lr) << 3;         // pre-swizzled col (halfs)
  const _Float16* gAb = A + (size_t)(m0 + w * 32 + lr) * K1 + lcs;
  const _Float16* gBb = B + (size_t)(n0 + w * 32 + lr) * K1 + lcs;
  const int ldso = (w * 32) * 64;              // LDS base (halfs)

#define STAGE(buf, kk) do {                                                   \
    _Pragma("unroll")                                                         \
    for (int j = 0; j < 4; ++j)                                               \
      gload_lds16(gAb + (kk) + j * 8 * K1, (_Float16*)&sA[buf][ldso + j*512]);\
    _Pragma("unroll")                                                         \
    for (int j = 0; j < 4; ++j)                                               \
      gload_lds16(gBb + (kk) + j * 8 * K1, (_Float16*)&sB[buf][ldso + j*512]);\
  } while (0)

  // fragment reads (XOR-swizzled): element (row,k) at idx (row*64+k)^((row&7)<<3)
#define LDA(AF, MH, buf) do {                                                 \
    _Pragma("unroll")                                                         \
    for (int m = 0; m < 4; ++m) {                                             \
      int row = wr * 128 + (MH) * 64 + m * 16 + (l & 15);                     \
      int k0 = (l >> 4) << 3;                                                 \
      int sw = (row & 7) << 3;                                                \
      AF[m][0] = *(const half8_t*)&sA[buf][(row * 64 + k0) ^ sw];             \
      AF[m][1] = *(const half8_t*)&sA[buf][(row * 64 + 32 + k0) ^ sw];        \
    }                                                                         \
  } while (0)

#define LDB_(BF, NH, buf) do {                                                \
    _Pragma("unroll")                                                         \
    for (int n = 0; n < 2; ++n) {                                             \
      int row = wc * 64 + (NH) * 32 + n * 16 + (l & 15);                      \
      int k0 = (l >> 4) << 3;                                                 \
      int sw = (row & 7) << 3;                                                \
      BF[n][0] = *(const half8_t*)&sB[buf][(row * 64 + k0) ^ sw];             \
      BF[n][1] = *(const half8_t*)&sB[buf][(row * 64 + 32 + k0) ^ sw];        \
    }                                                                         \
  } while (0)

#define MM(MH, NH, AF, BF) do {                                               \
    _Pragma("unroll")                                                         \
    for (int m = 0; m < 4; ++m)                                               \
      _Pragma("unroll")                                                       \
      for (int n = 0; n < 2; ++n) {                                           \
        acc[MH][NH][m][n] = __builtin_amdgcn_mfma_f32_16x16x32_f16(           \
            AF[m][0], BF[n][0], acc[MH][NH][m][n], 0, 0, 0);                  \
        acc[MH][NH][m][n] = __builtin_amdgcn_mfma_f32_16x16x32_f16(           \
            AF[m][1], BF[n][1], acc[MH][NH][m][n], 0, 0, 0);                  \
      }                                                                       \
  } while (0)

  f32x4_t acc[2][2][4][2] = {};

  STAGE(0, 0);
  STAGE(1, 64);
  VM8; BARX;

  for (int it = 0; it < NT1 / 2; ++it) {
    const int kn0 = it * 128 + 128;
    const int kn1 = it * 128 + 192;
    const int s0 = (kn0 < K1) ? kn0 : (K1 - 64);   // clamped: garbage, unread
    const int s1 = (kn1 < K1) ? kn1 : (K1 - 64);

    half8_t a0[4][2], a1[4][2], b0[2][2], b1[2][2];

    // ---- K-tile 2it (buf0), 4 phases ----
    LDA(a0, 0, 0); LDB_(b0, 0, 0);
    BARX; PR1; MM(0, 0, a0, b0); PR0; BARX;

    LDB_(b1, 1, 0);
    BARX; PR1; MM(0, 1, a0, b1); PR0; BARX;

    LDA(a1, 1, 0);
    BARX; PR1; MM(1, 0, a1, b0); PR0; BARX;

    STAGE(0, s0);
    BARX; PR1; MM(1, 1, a1, b1); PR0; VM8; BARX;

    // ---- K-tile 2it+1 (buf1), 4 phases ----
    LDA(a0, 0, 1); LDB_(b0, 0, 1);
    BARX; PR1; MM(0, 0, a0, b0); PR0; BARX;

    LDB_(b1, 1, 1);
    BARX; PR1; MM(0, 1, a0, b1); PR0; BARX;

    LDA(a1, 1, 1);
    BARX; PR1; MM(1, 0, a1, b0); PR0; BARX;

    STAGE(1, s1);
    BARX; PR1; MM(1, 1, a1, b1); PR0; VM8; BARX;
  }

  // ---- epilogue: block-uniform gate region ----
  const int region = n0 >> 10;               // 0=ig, 1=fg, 2=h
  const int cb = n0 & 1023;
#pragma unroll
  for (int mh = 0; mh < 2; ++mh)
#pragma unroll
    for (int m = 0; m < 4; ++m) {
      const int rbase = m0 + wr * 128 + mh * 64 + m * 16 + ((l >> 4) << 2);
#pragma unroll
      for (int r = 0; r < 4; ++r) {
        const int grow = rbase + r;
        const float* prow = part + (size_t)(grow >> 5) * NG + n0;
#pragma unroll
        for (int nh = 0; nh < 2; ++nh)
#pragma unroll
          for (int n = 0; n < 2; ++n) {
            const int lc = wc * 64 + nh * 32 + n * 16 + (l & 15);
            const float g = acc[mh][nh][m][n][r] + prow[lc];
            const size_t oi = (size_t)grow * HD + cb + lc;
            if (region == 0)      igb[oi] = (_Float16)sigmoidf_(g);
            else if (region == 1) out0[oi] = sigmoidf_(g);
            else                  th[oi] = (_Float16)tanhf_(g);
          }
      }
    }
#undef STAGE
#undef LDA
#undef LDB_
#undef MM
}

// ---------------- launch ----------------
extern "C" void kernel_launch(void* const* d_in, const int* in_sizes, int n_in,
                              void* d_out, int out_size, void* d_ws, size_t ws_size,
                              hipStream_t stream) {
  const float* x  = (const float*)d_in[0];
  const float* W1 = (const float*)d_in[1];
  const float* b1 = (const float*)d_in[2];
  const float* W2 = (const float*)d_in[3];
  const float* b2 = (const float*)d_in[4];
  float* out0 = (float*)d_out;                          // fg [4096][1024]
  float* out1 = out0 + (size_t)S_SEQ * HD;              // hr [4096][1024]

  char* ws = (char*)d_ws;
  _Float16* Ah    = (_Float16*)(ws);                        // 16 MiB [4096][2048]
  _Float16* w1h   = (_Float16*)(ws + ((size_t)16 << 20));   // 12 MiB [3072][2048]
  _Float16* w2h   = (_Float16*)(ws + ((size_t)28 << 20));   //  2 MiB [1024][1024]
  _Float16* xsumh = (_Float16*)(ws + ((size_t)30 << 20));   // .25MiB [128][1024]
  float*    praw  = (float*)   (ws + ((size_t)31 << 20));   // 1.5MiB [128][3072]
  float*    pout  = (float*)   (ws + ((size_t)33 << 20));   // 1.5MiB [128][3072]
  _Float16* igb   = (_Float16*)(ws + ((size_t)35 << 20));   //  8 MiB [4096][1024]
  _Float16* th    = (_Float16*)(ws + ((size_t)43 << 20));   //  8 MiB [4096][1024]

  conv_f32_f16<<<dim3(6144), dim3(256), 0, stream>>>(W1, w1h, NG * 2048 / 4);
  conv_f32_f16<<<dim3(1024), dim3(256), 0, stream>>>(W2, w2h, HD * HD / 4);

  scan_x<<<dim3(4, NCH), dim3(256), 0, stream>>>(x, Ah, xsumh);

  gemm_bt<0><<<dim3(NG / 128, 1), dim3(256), 0, stream>>>(
      xsumh, w1h + 1024, NCH, NG, HD, 2048, praw, nullptr, nullptr, nullptr);

  scan_part<<<dim3(NG / 256), dim3(256), 0, stream>>>(praw, b1, pout);

  gemm1_8ph<<<dim3(192), dim3(512), 0, stream>>>(Ah, w1h, pout, igb, out0, th);

  gemm_bt<1><<<dim3(HD / 128, S_SEQ / 128), dim3(256), 0, stream>>>(
      th, w2h, S_SEQ, HD, HD, HD, nullptr, b2, igb, out1);
}

// Round 4
// 157.054 us; speedup vs baseline: 1.0053x; 1.0053x over previous
//
#include <hip/hip_runtime.h>
#include <cmath>

#define S_SEQ 4096
#define HD 1024
#define NG 3072           // 3*H
#define CHR 32            // rows per scan chunk
#define NCH 128           // chunks (CHR*NCH = 4096)
#define K1 2048           // GEMM1 K
#define NT1 (K1 / 64)     // 32 K-tiles of 64

typedef _Float16 half8_t __attribute__((ext_vector_type(8)));
typedef _Float16 half4_t __attribute__((ext_vector_type(4)));
typedef float f32x4_t __attribute__((ext_vector_type(4)));

__device__ __forceinline__ void gload_lds16(const void* g, void* l) {
  __builtin_amdgcn_global_load_lds(
      (const __attribute__((address_space(1))) void*)g,
      (__attribute__((address_space(3))) void*)l, 16, 0, 0);
}

__device__ __forceinline__ float sigmoidf_(float x) {
  return 1.f / (1.f + __expf(-x));
}
__device__ __forceinline__ float tanhf_(float x) {
  return 1.f - 2.f / (__expf(2.f * x) + 1.f);
}

// ---------------- merged weight conversion (W1 then W2) --------------------
__global__ void conv_w(const float* __restrict__ W1, const float* __restrict__ W2,
                       _Float16* __restrict__ w1h, _Float16* __restrict__ w2h) {
  const int n1 = NG * 2048 / 4;            // W1 float4 count
  const int n2 = HD * HD / 4;              // W2 float4 count
  int i = blockIdx.x * 256 + threadIdx.x;
  if (i >= n1 + n2) return;
  const float* src = (i < n1) ? (W1 + (size_t)i * 4) : (W2 + (size_t)(i - n1) * 4);
  _Float16* dst = (i < n1) ? (w1h + (size_t)i * 4) : (w2h + (size_t)(i - n1) * 4);
  float4 v = *(const float4*)src;
  half4_t h;
  h[0] = (_Float16)v.x; h[1] = (_Float16)v.y;
  h[2] = (_Float16)v.z; h[3] = (_Float16)v.w;
  *(half4_t*)dst = h;
}

// ---------------- scan_x: A=[x | s_local] fp16, xsum=chunk sums fp16 -------
__global__ void scan_x(const float* __restrict__ x, _Float16* __restrict__ A,
                       _Float16* __restrict__ xsum) {
  int j = blockIdx.x * 256 + threadIdx.x;   // column 0..1023
  int c = blockIdx.y;                        // chunk 0..127
  int t0 = c * CHR;
  float run = 0.f;
  for (int t = t0; t < t0 + CHR; ++t) {
    float v = x[(size_t)t * HD + j];
    A[(size_t)t * 2048 + j]        = (_Float16)v;
    A[(size_t)t * 2048 + 1024 + j] = (_Float16)run;
    run += v;
  }
  xsum[(size_t)c * HD + j] = (_Float16)run;
}

// ---------------- exclusive scan over chunk partials + b1 fold -------------
__global__ void scan_part(const float* __restrict__ praw,
                          const float* __restrict__ b1,
                          float* __restrict__ pout) {
  int j = blockIdx.x * 256 + threadIdx.x;   // 0..3071
  float run = b1[j];
  for (int c = 0; c < NCH; ++c) {
    float v = praw[(size_t)c * NG + j];
    pout[(size_t)c * NG + j] = run;
    run += v;
  }
}

// ---------------- small 2-phase GEMM (partGEMM + GEMM2) --------------------
// MODE 0: C[row*N+col] = acc
// MODE 1: out[idx] = (acc + bias[col]) * (float)mulh[idx]
template <int MODE>
__global__ __launch_bounds__(256, 2)
void gemm_bt(const _Float16* __restrict__ A, const _Float16* __restrict__ B,
             int M, int N, int K, int ldb,
             float* __restrict__ C,
             const float* __restrict__ bias, const _Float16* __restrict__ mulh,
             float* __restrict__ out) {
  __shared__ _Float16 As[128 * 32];
  __shared__ _Float16 Bs[128 * 32];

  const int tid = threadIdx.x;
  const int lane = tid & 63;
  const int wid = tid >> 6;
  const int wr = wid >> 1;
  const int wc = wid & 1;

  const int m0 = blockIdx.y * 128;
  const int n0 = blockIdx.x * 128;

  const int srow = lane >> 2;
  const int scol = (lane & 3) << 3;

  const _Float16* gA = A + (size_t)(m0 + wid * 32 + srow) * K + scol;
  const _Float16* gB = B + (size_t)(n0 + wid * 32 + srow) * ldb + scol;
  _Float16* lA = As + (wid * 32) * 32;
  _Float16* lB = Bs + (wid * 32) * 32;

  f32x4_t acc[4][4] = {};

  const int fr = lane & 15;
  const int fk = (lane >> 4) << 3;

  for (int kk = 0; kk < K; kk += 32) {
    gload_lds16(gA + kk,                  lA);
    gload_lds16(gA + kk + (size_t)16*K,   lA + 16 * 32);
    gload_lds16(gB + kk,                  lB);
    gload_lds16(gB + kk + (size_t)16*ldb, lB + 16 * 32);
    __syncthreads();

    half8_t af[4], bf[4];
#pragma unroll
    for (int m = 0; m < 4; ++m)
      af[m] = *(const half8_t*)&As[(wr * 64 + m * 16 + fr) * 32 + fk];
#pragma unroll
    for (int n = 0; n < 4; ++n)
      bf[n] = *(const half8_t*)&Bs[(wc * 64 + n * 16 + fr) * 32 + fk];
#pragma unroll
    for (int m = 0; m < 4; ++m)
#pragma unroll
      for (int n = 0; n < 4; ++n)
        acc[m][n] = __builtin_amdgcn_mfma_f32_16x16x32_f16(af[m], bf[n],
                                                           acc[m][n], 0, 0, 0);
    __syncthreads();
  }

  const int crow = m0 + wr * 64 + ((lane >> 4) << 2);
  const int ccol = n0 + wc * 64 + (lane & 15);
#pragma unroll
  for (int m = 0; m < 4; ++m)
#pragma unroll
    for (int n = 0; n < 4; ++n) {
      const int col = ccol + n * 16;
#pragma unroll
      for (int r = 0; r < 4; ++r) {
        const int row = crow + m * 16 + r;
        const float v = acc[m][n][r];
        if (MODE == 0) {
          C[(size_t)row * N + col] = v;
        } else {
          size_t idx = (size_t)row * N + col;
          out[idx] = (v + bias[col]) * (float)mulh[idx];
        }
      }
    }
}

// ---------------- GEMM1: 256x256 tile, 8-phase, counted vmcnt --------------
// gates[4096,3072] = Ah[4096,2048] @ w1h[3072,2048]^T + part[(row>>5)][col]
#define BARX __builtin_amdgcn_s_barrier()
#define PR1 __builtin_amdgcn_s_setprio(1)
#define PR0 __builtin_amdgcn_s_setprio(0)
#define VM8 asm volatile("s_waitcnt vmcnt(8)" ::: "memory")

__global__ __launch_bounds__(512, 1)
void gemm1_8ph(const _Float16* __restrict__ A, const _Float16* __restrict__ B,
               const float* __restrict__ part, _Float16* __restrict__ igb,
               float* __restrict__ out0, _Float16* __restrict__ th) {
  __shared__ __align__(16) _Float16 sA[2][256 * 64];
  __shared__ __align__(16) _Float16 sB[2][256 * 64];

  const int tid = threadIdx.x;
  const int l = tid & 63;
  const int w = tid >> 6;          // 0..7
  const int wr = w >> 2;           // 0..1  (M half)
  const int wc = w & 3;            // 0..3  (N quarter)

  // bijective XCD swizzle: 192 blocks, 192 % 8 == 0
  const int id = blockIdx.x;
  const int swz = (id & 7) * 24 + (id >> 3);
  const int bx = swz % 12;         // N tile
  const int by = swz / 12;         // M tile
  const int m0 = by * 256;
  const int n0 = bx * 256;

  // staging: per wave rows [w*32, w*32+32); per gload 8 rows x 128B
  const int lr = l >> 3;                       // 0..7 row in octet
  const int lcs = ((l & 7) ^ lr) << 3;         // pre-swizzled col (halfs)
  const _Float16* gAb = A + (size_t)(m0 + w * 32 + lr) * K1 + lcs;
  const _Float16* gBb = B + (size_t)(n0 + w * 32 + lr) * K1 + lcs;
  const int ldso = (w * 32) * 64;              // LDS base (halfs)

#define STAGE(buf, kk) do {                                                   \
    _Pragma("unroll")                                                         \
    for (int j = 0; j < 4; ++j)                                               \
      gload_lds16(gAb + (kk) + j * 8 * K1, (_Float16*)&sA[buf][ldso + j*512]);\
    _Pragma("unroll")                                                         \
    for (int j = 0; j < 4; ++j)                                               \
      gload_lds16(gBb + (kk) + j * 8 * K1, (_Float16*)&sB[buf][ldso + j*512]);\
  } while (0)

#define LDA(AF, MH, buf) do {                                                 \
    _Pragma("unroll")                                                         \
    for (int m = 0; m < 4; ++m) {                                             \
      int row = wr * 128 + (MH) * 64 + m * 16 + (l & 15);                     \
      int k0 = (l >> 4) << 3;                                                 \
      int sw = (row & 7) << 3;                                                \
      AF[m][0] = *(const half8_t*)&sA[buf][(row * 64 + k0) ^ sw];             \
      AF[m][1] = *(const half8_t*)&sA[buf][(row * 64 + 32 + k0) ^ sw];        \
    }                                                                         \
  } while (0)

#define LDB_(BF, NH, buf) do {                                                \
    _Pragma("unroll")                                                         \
    for (int n = 0; n < 2; ++n) {                                             \
      int row = wc * 64 + (NH) * 32 + n * 16 + (l & 15);                      \
      int k0 = (l >> 4) << 3;                                                 \
      int sw = (row & 7) << 3;                                                \
      BF[n][0] = *(const half8_t*)&sB[buf][(row * 64 + k0) ^ sw];             \
      BF[n][1] = *(const half8_t*)&sB[buf][(row * 64 + 32 + k0) ^ sw];        \
    }                                                                         \
  } while (0)

#define MM(MH, NH, AF, BF) do {                                               \
    _Pragma("unroll")                                                         \
    for (int m = 0; m < 4; ++m)                                               \
      _Pragma("unroll")                                                       \
      for (int n = 0; n < 2; ++n) {                                           \
        acc[MH][NH][m][n] = __builtin_amdgcn_mfma_f32_16x16x32_f16(           \
            AF[m][0], BF[n][0], acc[MH][NH][m][n], 0, 0, 0);                  \
        acc[MH][NH][m][n] = __builtin_amdgcn_mfma_f32_16x16x32_f16(           \
            AF[m][1], BF[n][1], acc[MH][NH][m][n], 0, 0, 0);                  \
      }                                                                       \
  } while (0)

  f32x4_t acc[2][2][4][2] = {};

  STAGE(0, 0);
  STAGE(1, 64);
  VM8; BARX;

  for (int it = 0; it < NT1 / 2; ++it) {
    const int kn0 = it * 128 + 128;
    const int kn1 = it * 128 + 192;
    const int s0 = (kn0 < K1) ? kn0 : (K1 - 64);   // clamped: garbage, unread
    const int s1 = (kn1 < K1) ? kn1 : (K1 - 64);

    half8_t a0[4][2], a1[4][2], b0[2][2], b1[2][2];

    // ---- K-tile 2it (buf0), 4 phases ----
    LDA(a0, 0, 0); LDB_(b0, 0, 0);
    BARX; PR1; MM(0, 0, a0, b0); PR0; BARX;

    LDB_(b1, 1, 0);
    BARX; PR1; MM(0, 1, a0, b1); PR0; BARX;

    LDA(a1, 1, 0);
    BARX; PR1; MM(1, 0, a1, b0); PR0; BARX;

    STAGE(0, s0);
    BARX; PR1; MM(1, 1, a1, b1); PR0; VM8; BARX;

    // ---- K-tile 2it+1 (buf1), 4 phases ----
    LDA(a0, 0, 1); LDB_(b0, 0, 1);
    BARX; PR1; MM(0, 0, a0, b0); PR0; BARX;

    LDB_(b1, 1, 1);
    BARX; PR1; MM(0, 1, a0, b1); PR0; BARX;

    LDA(a1, 1, 1);
    BARX; PR1; MM(1, 0, a1, b0); PR0; BARX;

    STAGE(1, s1);
    BARX; PR1; MM(1, 1, a1, b1); PR0; VM8; BARX;
  }

  // ---- epilogue: block-uniform gate region ----
  const int region = n0 >> 10;               // 0=ig, 1=fg, 2=h
  const int cb = n0 & 1023;
#pragma unroll
  for (int mh = 0; mh < 2; ++mh)
#pragma unroll
    for (int m = 0; m < 4; ++m) {
      const int rbase = m0 + wr * 128 + mh * 64 + m * 16 + ((l >> 4) << 2);
#pragma unroll
      for (int r = 0; r < 4; ++r) {
        const int grow = rbase + r;
        const float* prow = part + (size_t)(grow >> 5) * NG + n0;
#pragma unroll
        for (int nh = 0; nh < 2; ++nh)
#pragma unroll
          for (int n = 0; n < 2; ++n) {
            const int lc = wc * 64 + nh * 32 + n * 16 + (l & 15);
            const float g = acc[mh][nh][m][n][r] + prow[lc];
            const size_t oi = (size_t)grow * HD + cb + lc;
            if (region == 0)      igb[oi] = (_Float16)sigmoidf_(g);
            else if (region == 1) out0[oi] = sigmoidf_(g);
            else                  th[oi] = (_Float16)tanhf_(g);
          }
      }
    }
#undef STAGE
#undef LDA
#undef LDB_
#undef MM
}

// ---------------- launch ----------------
extern "C" void kernel_launch(void* const* d_in, const int* in_sizes, int n_in,
                              void* d_out, int out_size, void* d_ws, size_t ws_size,
                              hipStream_t stream) {
  const float* x  = (const float*)d_in[0];
  const float* W1 = (const float*)d_in[1];
  const float* b1 = (const float*)d_in[2];
  const float* W2 = (const float*)d_in[3];
  const float* b2 = (const float*)d_in[4];
  float* out0 = (float*)d_out;                          // fg [4096][1024]
  float* out1 = out0 + (size_t)S_SEQ * HD;              // hr [4096][1024]

  char* ws = (char*)d_ws;
  _Float16* Ah    = (_Float16*)(ws);                        // 16 MiB [4096][2048]
  _Float16* w1h   = (_Float16*)(ws + ((size_t)16 << 20));   // 12 MiB [3072][2048]
  _Float16* w2h   = (_Float16*)(ws + ((size_t)28 << 20));   //  2 MiB [1024][1024]
  _Float16* xsumh = (_Float16*)(ws + ((size_t)30 << 20));   // .25MiB [128][1024]
  float*    praw  = (float*)   (ws + ((size_t)31 << 20));   // 1.5MiB [128][3072]
  float*    pout  = (float*)   (ws + ((size_t)33 << 20));   // 1.5MiB [128][3072]
  _Float16* igb   = (_Float16*)(ws + ((size_t)35 << 20));   //  8 MiB [4096][1024]
  _Float16* th    = (_Float16*)(ws + ((size_t)43 << 20));   //  8 MiB [4096][1024]

  conv_w<<<dim3(7168), dim3(256), 0, stream>>>(W1, W2, w1h, w2h);

  scan_x<<<dim3(4, NCH), dim3(256), 0, stream>>>(x, Ah, xsumh);

  gemm_bt<0><<<dim3(NG / 128, 1), dim3(256), 0, stream>>>(
      xsumh, w1h + 1024, NCH, NG, HD, 2048, praw, nullptr, nullptr, nullptr);

  scan_part<<<dim3(NG / 256), dim3(256), 0, stream>>>(praw, b1, pout);

  gemm1_8ph<<<dim3(192), dim3(512), 0, stream>>>(Ah, w1h, pout, igb, out0, th);

  gemm_bt<1><<<dim3(HD / 128, S_SEQ / 128), dim3(256), 0, stream>>>(
      th, w2h, S_SEQ, HD, HD, HD, nullptr, b2, igb, out1);
}

// Round 5
// 150.777 us; speedup vs baseline: 1.0472x; 1.0416x over previous
//
#include <hip/hip_runtime.h>
#include <cmath>

#define S_SEQ 4096
#define HD 1024
#define NG 3072           // 3*H
#define CHR 32            // rows per scan chunk
#define NCH 128           // chunks (CHR*NCH = 4096)

typedef _Float16 half8_t __attribute__((ext_vector_type(8)));
typedef _Float16 half4_t __attribute__((ext_vector_type(4)));
typedef float f32x4_t __attribute__((ext_vector_type(4)));

__device__ __forceinline__ void gload_lds16(const void* g, void* l) {
  __builtin_amdgcn_global_load_lds(
      (const __attribute__((address_space(1))) void*)g,
      (__attribute__((address_space(3))) void*)l, 16, 0, 0);
}

__device__ __forceinline__ float sigmoidf_(float x) {
  return 1.f / (1.f + __expf(-x));
}
__device__ __forceinline__ float tanhf_(float x) {
  return 1.f - 2.f / (__expf(2.f * x) + 1.f);
}

// ---------------- prep: weight conversion + scan_x merged ------------------
// blocks [0, 7168): conv W1 (6144) then W2 (1024), one float4 per thread
// blocks [7168, 7680): scan_x — 4 col-blocks x 128 chunks
#define CONV_BLOCKS 7168
__global__ void prep(const float* __restrict__ W1, const float* __restrict__ W2,
                     _Float16* __restrict__ w1h, _Float16* __restrict__ w2h,
                     const float* __restrict__ x, _Float16* __restrict__ A,
                     _Float16* __restrict__ xsum) {
  const int bid = blockIdx.x;
  if (bid < CONV_BLOCKS) {
    const int n1 = NG * 2048 / 4;
    int i = bid * 256 + threadIdx.x;
    const float* src = (i < n1) ? (W1 + (size_t)i * 4)
                                : (W2 + (size_t)(i - n1) * 4);
    _Float16* dst = (i < n1) ? (w1h + (size_t)i * 4)
                             : (w2h + (size_t)(i - n1) * 4);
    float4 v = *(const float4*)src;
    half4_t h;
    h[0] = (_Float16)v.x; h[1] = (_Float16)v.y;
    h[2] = (_Float16)v.z; h[3] = (_Float16)v.w;
    *(half4_t*)dst = h;
  } else {
    const int sx = bid - CONV_BLOCKS;
    const int j = (sx & 3) * 256 + threadIdx.x;   // column 0..1023
    const int c = sx >> 2;                        // chunk 0..127
    const int t0 = c * CHR;
    float run = 0.f;
    for (int t = t0; t < t0 + CHR; ++t) {
      float v = x[(size_t)t * HD + j];
      A[(size_t)t * 2048 + j]        = (_Float16)v;
      A[(size_t)t * 2048 + 1024 + j] = (_Float16)run;
      run += v;
    }
    xsum[(size_t)c * HD + j] = (_Float16)run;
  }
}

// ---------------- exclusive scan over chunk partials + b1 fold -------------
// 8x unrolled: loads are independent of the running sum -> ILP hides latency
__global__ void scan_part(const float* __restrict__ praw,
                          const float* __restrict__ b1,
                          float* __restrict__ pout) {
  int j = blockIdx.x * 256 + threadIdx.x;   // 0..3071
  float run = b1[j];
  for (int c = 0; c < NCH; c += 8) {
    float v[8];
#pragma unroll
    for (int u = 0; u < 8; ++u)
      v[u] = praw[(size_t)(c + u) * NG + j];
#pragma unroll
    for (int u = 0; u < 8; ++u) {
      pout[(size_t)(c + u) * NG + j] = run;
      run += v[u];
    }
  }
}

// ---------------- GEMM: [M,N] = A[M,K] @ B[N,K-strided ldb]^T --------------
// MODE 0: C[row*N+col] = acc                                (part GEMM)
// MODE 1: out[idx] = (acc + bias[col]) * (float)mulh[idx]   (GEMM2 -> hr)
// MODE 2: g = acc + part[(row>>5)*NG + col]; gate epilogue  (GEMM1)
template <int MODE>
__global__ __launch_bounds__(256, 2)
void gemm_bt(const _Float16* __restrict__ A, const _Float16* __restrict__ B,
             int M, int N, int K, int ldb,
             float* __restrict__ C,
             const float* __restrict__ bias, const _Float16* __restrict__ mulh,
             float* __restrict__ out,
             const float* __restrict__ part, _Float16* __restrict__ igb,
             _Float16* __restrict__ th) {
  __shared__ _Float16 As[128 * 32];
  __shared__ _Float16 Bs[128 * 32];

  const int tid = threadIdx.x;
  const int lane = tid & 63;
  const int wid = tid >> 6;
  const int wr = wid >> 1;
  const int wc = wid & 1;

  const int m0 = blockIdx.y * 128;
  const int n0 = blockIdx.x * 128;

  const int srow = lane >> 2;
  const int scol = (lane & 3) << 3;

  const _Float16* gA = A + (size_t)(m0 + wid * 32 + srow) * K + scol;
  const _Float16* gB = B + (size_t)(n0 + wid * 32 + srow) * ldb + scol;
  _Float16* lA = As + (wid * 32) * 32;
  _Float16* lB = Bs + (wid * 32) * 32;

  f32x4_t acc[4][4] = {};

  const int fr = lane & 15;
  const int fk = (lane >> 4) << 3;

  for (int kk = 0; kk < K; kk += 32) {
    gload_lds16(gA + kk,                  lA);
    gload_lds16(gA + kk + (size_t)16*K,   lA + 16 * 32);
    gload_lds16(gB + kk,                  lB);
    gload_lds16(gB + kk + (size_t)16*ldb, lB + 16 * 32);
    __syncthreads();

    half8_t af[4], bf[4];
#pragma unroll
    for (int m = 0; m < 4; ++m)
      af[m] = *(const half8_t*)&As[(wr * 64 + m * 16 + fr) * 32 + fk];
#pragma unroll
    for (int n = 0; n < 4; ++n)
      bf[n] = *(const half8_t*)&Bs[(wc * 64 + n * 16 + fr) * 32 + fk];
#pragma unroll
    for (int m = 0; m < 4; ++m)
#pragma unroll
      for (int n = 0; n < 4; ++n)
        acc[m][n] = __builtin_amdgcn_mfma_f32_16x16x32_f16(af[m], bf[n],
                                                           acc[m][n], 0, 0, 0);
    __syncthreads();
  }

  const int crow = m0 + wr * 64 + ((lane >> 4) << 2);
  const int ccol = n0 + wc * 64 + (lane & 15);
#pragma unroll
  for (int m = 0; m < 4; ++m)
#pragma unroll
    for (int n = 0; n < 4; ++n) {
      const int col = ccol + n * 16;
#pragma unroll
      for (int r = 0; r < 4; ++r) {
        const int row = crow + m * 16 + r;
        const float v = acc[m][n][r];
        if (MODE == 0) {
          C[(size_t)row * N + col] = v;
        } else if (MODE == 1) {
          size_t idx = (size_t)row * N + col;
          out[idx] = (v + bias[col]) * (float)mulh[idx];
        } else {
          float g = v + part[(size_t)(row >> 5) * NG + col];
          if (col < 1024)
            igb[(size_t)row * HD + col] = (_Float16)sigmoidf_(g);
          else if (col < 2048)
            out[(size_t)row * HD + (col - 1024)] = sigmoidf_(g);
          else
            th[(size_t)row * HD + (col - 2048)] = (_Float16)tanhf_(g);
        }
      }
    }
}

// ---------------- launch ----------------
extern "C" void kernel_launch(void* const* d_in, const int* in_sizes, int n_in,
                              void* d_out, int out_size, void* d_ws, size_t ws_size,
                              hipStream_t stream) {
  const float* x  = (const float*)d_in[0];
  const float* W1 = (const float*)d_in[1];
  const float* b1 = (const float*)d_in[2];
  const float* W2 = (const float*)d_in[3];
  const float* b2 = (const float*)d_in[4];
  float* out0 = (float*)d_out;                          // fg [4096][1024]
  float* out1 = out0 + (size_t)S_SEQ * HD;              // hr [4096][1024]

  char* ws = (char*)d_ws;
  _Float16* Ah    = (_Float16*)(ws);                        // 16 MiB [4096][2048]
  _Float16* w1h   = (_Float16*)(ws + ((size_t)16 << 20));   // 12 MiB [3072][2048]
  _Float16* w2h   = (_Float16*)(ws + ((size_t)28 << 20));   //  2 MiB [1024][1024]
  _Float16* xsumh = (_Float16*)(ws + ((size_t)30 << 20));   // .25MiB [128][1024]
  float*    praw  = (float*)   (ws + ((size_t)31 << 20));   // 1.5MiB [128][3072]
  float*    pout  = (float*)   (ws + ((size_t)33 << 20));   // 1.5MiB [128][3072]
  _Float16* igb   = (_Float16*)(ws + ((size_t)35 << 20));   //  8 MiB [4096][1024]
  _Float16* th    = (_Float16*)(ws + ((size_t)43 << 20));   //  8 MiB [4096][1024]

  prep<<<dim3(CONV_BLOCKS + 512), dim3(256), 0, stream>>>(
      W1, W2, w1h, w2h, x, Ah, xsumh);

  gemm_bt<0><<<dim3(NG / 128, 1), dim3(256), 0, stream>>>(
      xsumh, w1h + 1024, NCH, NG, HD, 2048,
      praw, nullptr, nullptr, nullptr, nullptr, nullptr, nullptr);

  scan_part<<<dim3(NG / 256), dim3(256), 0, stream>>>(praw, b1, pout);

  gemm_bt<2><<<dim3(NG / 128, S_SEQ / 128), dim3(256), 0, stream>>>(
      Ah, w1h, S_SEQ, NG, 2048, 2048,
      nullptr, nullptr, nullptr, out0, pout, igb, th);

  gemm_bt<1><<<dim3(HD / 128, S_SEQ / 128), dim3(256), 0, stream>>>(
      th, w2h, S_SEQ, HD, HD, HD,
      nullptr, b2, igb, out1, nullptr, nullptr, nullptr);
}

// Round 6
// 147.724 us; speedup vs baseline: 1.0688x; 1.0207x over previous
//
#include <hip/hip_runtime.h>
#include <cmath>

#define S_SEQ 4096
#define HD 1024
#define NG 3072           // 3*H
#define CHR 32            // rows per scan chunk
#define NCH 128           // chunks (CHR*NCH = 4096)

typedef _Float16 half8_t __attribute__((ext_vector_type(8)));
typedef _Float16 half4_t __attribute__((ext_vector_type(4)));
typedef float f32x4_t __attribute__((ext_vector_type(4)));

__device__ __forceinline__ void gload_lds16(const void* g, void* l) {
  __builtin_amdgcn_global_load_lds(
      (const __attribute__((address_space(1))) void*)g,
      (__attribute__((address_space(3))) void*)l, 16, 0, 0);
}

__device__ __forceinline__ float sigmoidf_(float x) {
  return 1.f / (1.f + __expf(-x));
}
__device__ __forceinline__ float tanhf_(float x) {
  return 1.f - 2.f / (__expf(2.f * x) + 1.f);
}

// ---------------- prep: weight conversion + scan_x merged ------------------
#define CONV_BLOCKS 7168
__global__ void prep(const float* __restrict__ W1, const float* __restrict__ W2,
                     _Float16* __restrict__ w1h, _Float16* __restrict__ w2h,
                     const float* __restrict__ x, _Float16* __restrict__ A,
                     _Float16* __restrict__ xsum) {
  const int bid = blockIdx.x;
  if (bid < CONV_BLOCKS) {
    const int n1 = NG * 2048 / 4;
    int i = bid * 256 + threadIdx.x;
    const float* src = (i < n1) ? (W1 + (size_t)i * 4)
                                : (W2 + (size_t)(i - n1) * 4);
    _Float16* dst = (i < n1) ? (w1h + (size_t)i * 4)
                             : (w2h + (size_t)(i - n1) * 4);
    float4 v = *(const float4*)src;
    half4_t h;
    h[0] = (_Float16)v.x; h[1] = (_Float16)v.y;
    h[2] = (_Float16)v.z; h[3] = (_Float16)v.w;
    *(half4_t*)dst = h;
  } else {
    const int sx = bid - CONV_BLOCKS;
    const int j = (sx & 3) * 256 + threadIdx.x;   // column 0..1023
    const int c = sx >> 2;                        // chunk 0..127
    const int t0 = c * CHR;
    float run = 0.f;
    for (int t = t0; t < t0 + CHR; ++t) {
      float v = x[(size_t)t * HD + j];
      A[(size_t)t * 2048 + j]        = (_Float16)v;
      A[(size_t)t * 2048 + 1024 + j] = (_Float16)run;
      run += v;
    }
    xsum[(size_t)c * HD + j] = (_Float16)run;
  }
}

// ---------------- exclusive scan over 4 K-split partials + b1 --------------
__global__ void scan_part(const float* __restrict__ praw,
                          const float* __restrict__ b1,
                          float* __restrict__ pout) {
  int j = blockIdx.x * 256 + threadIdx.x;   // 0..3071
  const size_t SP = (size_t)NCH * NG;
  float run = b1[j];
  for (int c = 0; c < NCH; c += 8) {
    float v[8];
#pragma unroll
    for (int u = 0; u < 8; ++u) {
      size_t i0 = (size_t)(c + u) * NG + j;
      v[u] = (praw[i0] + praw[i0 + SP]) + (praw[i0 + 2 * SP] + praw[i0 + 3 * SP]);
    }
#pragma unroll
    for (int u = 0; u < 8; ++u) {
      pout[(size_t)(c + u) * NG + j] = run;
      run += v[u];
    }
  }
}

// ---------------- partGEMM: praw4[z] = xsum @ W1b^T over K window z --------
__global__ __launch_bounds__(256, 2)
void gemm_part(const _Float16* __restrict__ A, const _Float16* __restrict__ B,
               float* __restrict__ C) {
  __shared__ _Float16 As[128 * 32];
  __shared__ _Float16 Bs[128 * 32];

  const int tid = threadIdx.x;
  const int lane = tid & 63;
  const int wid = tid >> 6;
  const int wr = wid >> 1;
  const int wc = wid & 1;

  const int n0 = blockIdx.x * 128;
  const int koff = blockIdx.z * 256;

  const int srow = lane >> 2;
  const int scol = (lane & 3) << 3;

  const _Float16* gA = A + (size_t)(wid * 32 + srow) * 1024 + koff + scol;
  const _Float16* gB = B + (size_t)(n0 + wid * 32 + srow) * 2048 + koff + scol;
  _Float16* lA = As + (wid * 32) * 32;
  _Float16* lB = Bs + (wid * 32) * 32;

  f32x4_t acc[4][4] = {};

  const int fr = lane & 15;
  const int fk = (lane >> 4) << 3;

  for (int kk = 0; kk < 256; kk += 32) {
    gload_lds16(gA + kk,                    lA);
    gload_lds16(gA + kk + (size_t)16*1024,  lA + 16 * 32);
    gload_lds16(gB + kk,                    lB);
    gload_lds16(gB + kk + (size_t)16*2048,  lB + 16 * 32);
    __syncthreads();

    half8_t af[4], bf[4];
#pragma unroll
    for (int m = 0; m < 4; ++m)
      af[m] = *(const half8_t*)&As[(wr * 64 + m * 16 + fr) * 32 + fk];
#pragma unroll
    for (int n = 0; n < 4; ++n)
      bf[n] = *(const half8_t*)&Bs[(wc * 64 + n * 16 + fr) * 32 + fk];
#pragma unroll
    for (int m = 0; m < 4; ++m)
#pragma unroll
      for (int n = 0; n < 4; ++n)
        acc[m][n] = __builtin_amdgcn_mfma_f32_16x16x32_f16(af[m], bf[n],
                                                           acc[m][n], 0, 0, 0);
    __syncthreads();
  }

  float* Cz = C + (size_t)blockIdx.z * NCH * NG;
  const int crow = wr * 64 + ((lane >> 4) << 2);
  const int ccol = n0 + wc * 64 + fr;
#pragma unroll
  for (int m = 0; m < 4; ++m)
#pragma unroll
    for (int n = 0; n < 4; ++n) {
      const int col = ccol + n * 16;
#pragma unroll
      for (int r = 0; r < 4; ++r)
        Cz[(size_t)(crow + m * 16 + r) * NG + col] = acc[m][n][r];
    }
}

// ---------------- triple-buffered counted-vmcnt GEMM -----------------------
// MODE 1: outf[idx] = (acc + bias[col]) * (float)mulh[idx]   (GEMM2)
// MODE 2: g = acc + part[(row>>5)*NG + col]; gate epilogue   (GEMM1)
#define BARX __builtin_amdgcn_s_barrier()
#define PR1 __builtin_amdgcn_s_setprio(1)
#define PR0 __builtin_amdgcn_s_setprio(0)
#define VM4 asm volatile("s_waitcnt vmcnt(4)" ::: "memory")

template <int NTILE, int MODE>
__global__ __launch_bounds__(256, 3)
void gemm_t3(const _Float16* __restrict__ A, const _Float16* __restrict__ B,
             int N,
             const float* __restrict__ part, _Float16* __restrict__ igb,
             float* __restrict__ outf, _Float16* __restrict__ th,
             const float* __restrict__ bias, const _Float16* __restrict__ mulh) {
  constexpr int KS = NTILE * 32;       // K = row stride of A and B
  __shared__ __align__(16) _Float16 sA[3][128 * 32];
  __shared__ __align__(16) _Float16 sB[3][128 * 32];

  const int tid = threadIdx.x;
  const int l = tid & 63;
  const int wid = tid >> 6;
  const int wr = wid >> 1;
  const int wc = wid & 1;
  const int m0 = blockIdx.y * 128;
  const int n0 = blockIdx.x * 128;

  // staging: thread covers row (srow [+64]), pre-swizzled 16B chunk of 64B row
  const int srow = tid >> 2;                        // 0..63
  const int schunk = (tid & 3) ^ ((tid >> 3) & 3);  // inverse of read swizzle
  const _Float16* gA = A + (size_t)(m0 + srow) * KS + schunk * 8;
  const _Float16* gB = B + (size_t)(n0 + srow) * KS + schunk * 8;
  const int ldst = tid * 8;                         // linear LDS dest (halfs)

#define STG(bn, kt) do {                                              \
    const int kk_ = (kt) * 32;                                        \
    gload_lds16(gA + kk_,           &sA[bn][ldst]);                   \
    gload_lds16(gA + kk_ + 64 * KS, &sA[bn][2048 + ldst]);            \
    gload_lds16(gB + kk_,           &sB[bn][ldst]);                   \
    gload_lds16(gB + kk_ + 64 * KS, &sB[bn][2048 + ldst]);            \
  } while (0)

  const int fr = l & 15;
  // read swizzle: chunk' = chunk ^ ((row>>1)&3); row≡fr (mod 16-blocks)
  const int kidx = (((l >> 4) ^ ((l >> 1) & 3)) << 3);

  f32x4_t acc[4][4] = {};

#define BODY(kt, bc, bn) do {                                         \
    int ks_ = (kt) + 2; if (ks_ > NTILE - 1) ks_ = NTILE - 1;         \
    STG(bn, ks_);                                                     \
    half8_t af[4], bf[4];                                             \
    _Pragma("unroll")                                                 \
    for (int m = 0; m < 4; ++m)                                       \
      af[m] = *(const half8_t*)&sA[bc][(wr*64 + m*16 + fr)*32 + kidx];\
    _Pragma("unroll")                                                 \
    for (int n = 0; n < 4; ++n)                                       \
      bf[n] = *(const half8_t*)&sB[bc][(wc*64 + n*16 + fr)*32 + kidx];\
    PR1;                                                              \
    _Pragma("unroll")                                                 \
    for (int m = 0; m < 4; ++m)                                       \
      _Pragma("unroll")                                               \
      for (int n = 0; n < 4; ++n)                                     \
        acc[m][n] = __builtin_amdgcn_mfma_f32_16x16x32_f16(           \
            af[m], bf[n], acc[m][n], 0, 0, 0);                        \
    PR0;                                                              \
    VM4; BARX;                                                        \
  } while (0)

  STG(0, 0);
  STG(1, 1);
  VM4; BARX;

#pragma unroll 1
  for (int t3 = 0; t3 < NTILE / 3; ++t3) {
    const int kt = t3 * 3;
    BODY(kt,     0, 2);
    BODY(kt + 1, 1, 0);
    BODY(kt + 2, 2, 1);
  }
  if constexpr (NTILE % 3 >= 1) BODY(NTILE - NTILE % 3,     0, 2);
  if constexpr (NTILE % 3 >= 2) BODY(NTILE - NTILE % 3 + 1, 1, 0);

  // ---- epilogue ----
  const int crow = m0 + wr * 64 + ((l >> 4) << 2);
  const int ccol = n0 + wc * 64 + fr;
#pragma unroll
  for (int m = 0; m < 4; ++m)
#pragma unroll
    for (int n = 0; n < 4; ++n) {
      const int col = ccol + n * 16;
#pragma unroll
      for (int r = 0; r < 4; ++r) {
        const int row = crow + m * 16 + r;
        const float v = acc[m][n][r];
        if (MODE == 1) {
          size_t idx = (size_t)row * N + col;
          outf[idx] = (v + bias[col]) * (float)mulh[idx];
        } else {
          float g = v + part[(size_t)(row >> 5) * NG + col];
          if (col < 1024)
            igb[(size_t)row * HD + col] = (_Float16)sigmoidf_(g);
          else if (col < 2048)
            outf[(size_t)row * HD + (col - 1024)] = sigmoidf_(g);
          else
            th[(size_t)row * HD + (col - 2048)] = (_Float16)tanhf_(g);
        }
      }
    }
#undef STG
#undef BODY
}

// ---------------- launch ----------------
extern "C" void kernel_launch(void* const* d_in, const int* in_sizes, int n_in,
                              void* d_out, int out_size, void* d_ws, size_t ws_size,
                              hipStream_t stream) {
  const float* x  = (const float*)d_in[0];
  const float* W1 = (const float*)d_in[1];
  const float* b1 = (const float*)d_in[2];
  const float* W2 = (const float*)d_in[3];
  const float* b2 = (const float*)d_in[4];
  float* out0 = (float*)d_out;                          // fg [4096][1024]
  float* out1 = out0 + (size_t)S_SEQ * HD;              // hr [4096][1024]

  char* ws = (char*)d_ws;
  _Float16* Ah    = (_Float16*)(ws);                        // 16 MiB [4096][2048]
  _Float16* w1h   = (_Float16*)(ws + ((size_t)16 << 20));   // 12 MiB [3072][2048]
  _Float16* w2h   = (_Float16*)(ws + ((size_t)28 << 20));   //  2 MiB [1024][1024]
  _Float16* xsumh = (_Float16*)(ws + ((size_t)30 << 20));   // .25MiB [128][1024]
  float*    praw4 = (float*)   (ws + ((size_t)31 << 20));   //  6 MiB [4][128][3072]
  float*    pout  = (float*)   (ws + ((size_t)37 << 20));   // 1.5MiB [128][3072]
  _Float16* igb   = (_Float16*)(ws + ((size_t)39 << 20));   //  8 MiB [4096][1024]
  _Float16* th    = (_Float16*)(ws + ((size_t)47 << 20));   //  8 MiB [4096][1024]

  prep<<<dim3(CONV_BLOCKS + 512), dim3(256), 0, stream>>>(
      W1, W2, w1h, w2h, x, Ah, xsumh);

  gemm_part<<<dim3(NG / 128, 1, 4), dim3(256), 0, stream>>>(
      xsumh, w1h + 1024, praw4);

  scan_part<<<dim3(NG / 256), dim3(256), 0, stream>>>(praw4, b1, pout);

  gemm_t3<64, 2><<<dim3(NG / 128, S_SEQ / 128), dim3(256), 0, stream>>>(
      Ah, w1h, NG, pout, igb, out0, th, nullptr, nullptr);

  gemm_t3<32, 1><<<dim3(HD / 128, S_SEQ / 128), dim3(256), 0, stream>>>(
      th, w2h, HD, nullptr, nullptr, out1, nullptr, b2, igb);
}